// Round 8
// baseline (87.997 us; speedup 1.0000x reference)
//
#include <hip/hip_runtime.h>

using bf16x8   = __attribute__((ext_vector_type(8))) __bf16;
using f32x4    = __attribute__((ext_vector_type(4))) float;
using f32x16   = __attribute__((ext_vector_type(16))) float;
using floatv4  = __attribute__((ext_vector_type(4))) float;
using ushortv4 = __attribute__((ext_vector_type(4))) unsigned short;
using ushortv8 = __attribute__((ext_vector_type(8))) unsigned short;
using uintv2   = __attribute__((ext_vector_type(2))) unsigned int;
using uintv4   = __attribute__((ext_vector_type(4))) unsigned int;

#define N_SEQ 4096
#define N_B   4
#define DIMK  1024
#define HS    128
#define ROWS  (N_B * N_SEQ)
#define KVB   32
#define TT    (N_SEQ / KVB)   // 128 kv tiles
#define CEXPF 0.045084220027780106f   // log2(e)/32

__device__ __forceinline__ unsigned short f2bf(float f) {
    unsigned u = __builtin_bit_cast(unsigned, f);
    u += 0x7FFFu + ((u >> 16) & 1u);   // RNE
    return (unsigned short)(u >> 16);
}

__device__ __forceinline__ unsigned cvtpk(float lo, float hi) {
    unsigned r;
    asm("v_cvt_pk_bf16_f32 %0, %1, %2" : "=v"(r) : "v"(lo), "v"(hi));
    return r;
}

__device__ __forceinline__ void gload16(const unsigned short* g, unsigned short* l) {
    __builtin_amdgcn_global_load_lds(
        (const __attribute__((address_space(1))) unsigned int*)g,
        (__attribute__((address_space(3))) unsigned int*)l, 16, 0, 0);
}

// ---------------- castw: W -> bf16, pre-permuted image for proj's LDS, Wq pre-scaled ----------------
// Wb2 layout: [32 ks][3 z][128 row][4 slot_phys][8 shorts]
// content(row, slot_phys) = W[row][ks*32 + slot_log*8 ..+7], slot_log = (slot_phys - (row>>1)) & 3
__global__ __launch_bounds__(256) void castw_kernel(
    const float* __restrict__ Wq,
    const float* __restrict__ Wk,
    const float* __restrict__ Wv,
    unsigned short* __restrict__ Wb2)
{
    const int blk = blockIdx.x;           // [0,192): 64 blocks per z
    const int z = blk >> 6;
    const int b2 = blk & 63;
    const float* src = (z == 0) ? Wq : (z == 1) ? Wk : Wv;
    const float scale = (z == 0) ? CEXPF : 1.0f;

    const int oo = b2 * 256 + threadIdx.x;        // slot-unit index within z: [0, 16384)
    const int slot = oo & 3;
    const int row  = (oo >> 2) & 127;
    const int ks   = oo >> 9;
    const int slog = (slot - (row >> 1)) & 3;
    const int k0   = ks * 32 + slog * 8;

    floatv4 a = *reinterpret_cast<const floatv4*>(src + (size_t)row * DIMK + k0);
    floatv4 b = *reinterpret_cast<const floatv4*>(src + (size_t)row * DIMK + k0 + 4);
    ushortv8 o = { f2bf(a.x*scale), f2bf(a.y*scale), f2bf(a.z*scale), f2bf(a.w*scale),
                   f2bf(b.x*scale), f2bf(b.y*scale), f2bf(b.z*scale), f2bf(b.w*scale) };
    unsigned short* dst = Wb2 + (size_t)ks * 12288 + (size_t)z * 4096 + ((row * 4 + slot) * 8);
    *reinterpret_cast<ushortv8*>(dst) = o;
}

// ---------------- single-pass projection: Q,K,V from one X read ----------------
// grid 256, block 512 = 8 waves. Block: 64 X-rows x 384 out cols (3z x 128).
// Wave wv owns cols wv*48 .. +47 (3 x 16-col frags). BK=32, counted-vmcnt 2-buffer.
__global__ __launch_bounds__(512, 1) void proj_kernel(
    const float* __restrict__ X,
    const unsigned short* __restrict__ Wb2,
    unsigned short* __restrict__ Qb,
    unsigned short* __restrict__ Kb,
    unsigned short* __restrict__ Vt)
{
    const int row0 = blockIdx.x * 64;
    __shared__ unsigned short smem[2 * 64 * 40 + 2 * 384 * 32];  // Xs[2][64][40] | Ws[2][384][32]
    unsigned short* Xs = smem;
    unsigned short* Ws = smem + 2 * 64 * 40;
    const int tid = threadIdx.x;
    const int wv = tid >> 6, lane = tid & 63;
    const int lr = lane & 15, lg = lane >> 4;

    const int xr_r = tid >> 3, xr_q = tid & 7;   // X slice staging: row, float4-chunk
    const float* xgbase = X + (size_t)(row0 + xr_r) * DIMK + xr_q * 4;

    f32x4 acc[4][3] = {};

    auto loadX = [&](floatv4& xr, int ks) {
        xr = *reinterpret_cast<const floatv4*>(xgbase + ks * 32);
    };
    auto writeX = [&](int buf, const floatv4& xr) {
        uintv2 w = { cvtpk(xr.x, xr.y), cvtpk(xr.z, xr.w) };
        *reinterpret_cast<uintv2*>(&Xs[buf * (64 * 40) + xr_r * 40 + xr_q * 4]) = w;
    };
    auto stageW = [&](int buf, int ks) {
        const unsigned short* src = Wb2 + (size_t)ks * 12288;
        unsigned short* dst = Ws + buf * 12288;
        #pragma unroll
        for (int jj = 0; jj < 3; ++jj)
            gload16(src + (size_t)(jj * 512 + wv * 64 + lane) * 8,
                    dst + (jj * 512 + wv * 64) * 8);
    };

    // fragment geometry (z never straddles a 16-col frag: 48*wv+16*ni, 128%16==0)
    int zni[3], wrow0[3];
    #pragma unroll
    for (int ni = 0; ni < 3; ++ni) {
        int gc0 = wv * 48 + ni * 16;
        zni[ni] = gc0 >> 7;
        wrow0[ni] = gc0 & 127;
    }

    floatv4 xrA, xrB;
    // prologue: 2 tiles in flight
    loadX(xrB, 0); stageW(0, 0);
    loadX(xrA, 1); stageW(1, 1);
    asm volatile("s_waitcnt vmcnt(4)" ::: "memory");   // X0, W0 done
    writeX(0, xrB);
    __syncthreads();

#define PROJ_ITER(KS, XN, XM, CUR)                                             \
    {                                                                          \
        const unsigned short* Xc = Xs + (CUR) * (64 * 40);                     \
        const unsigned short* Wc = Ws + (CUR) * 12288;                         \
        bf16x8 af[4]; bf16x8 bfr[3];                                           \
        _Pragma("unroll")                                                      \
        for (int mi = 0; mi < 4; ++mi)                                         \
            af[mi] = *reinterpret_cast<const bf16x8*>(                         \
                &Xc[(mi * 16 + lr) * 40 + lg * 8]);                            \
        _Pragma("unroll")                                                      \
        for (int ni = 0; ni < 3; ++ni) {                                       \
            int wrow = wrow0[ni] + lr;                                         \
            bfr[ni] = *reinterpret_cast<const bf16x8*>(                        \
                &Wc[((zni[ni] * 128 + wrow) * 4 + ((lg + (wrow >> 1)) & 3)) * 8]); \
        }                                                                      \
        _Pragma("unroll")                                                      \
        for (int mi = 0; mi < 4; ++mi)                                         \
            _Pragma("unroll")                                                  \
            for (int ni = 0; ni < 3; ++ni)                                     \
                acc[mi][ni] = __builtin_amdgcn_mfma_f32_16x16x32_bf16(         \
                    af[mi], bfr[ni], acc[mi][ni], 0, 0, 0);                    \
        __syncthreads();                                                       \
        if ((KS) + 2 < 32) { loadX(XM, (KS) + 2); stageW((CUR), (KS) + 2); }   \
        if ((KS) + 1 < 32) {                                                   \
            if ((KS) + 2 < 32)                                                 \
                asm volatile("s_waitcnt vmcnt(4)" ::: "memory");               \
            else                                                               \
                asm volatile("s_waitcnt vmcnt(0)" ::: "memory");               \
            writeX((CUR) ^ 1, XN);                                             \
            __syncthreads();                                                   \
        }                                                                      \
    }

    for (int kss = 0; kss < 32; kss += 2) {
        PROJ_ITER(kss,     xrA, xrB, 0);
        PROJ_ITER(kss + 1, xrB, xrA, 1);
    }
#undef PROJ_ITER

    // ---- epilogue: Q/K direct stores, V via LDS transpose ----
    unsigned short* Cs = smem;   // [64][136] overlay (last barrier above protects)
    #pragma unroll
    for (int ni = 0; ni < 3; ++ni) {
        const int z = zni[ni];
        if (z < 2) {
            unsigned short* O = (z == 0) ? Qb : Kb;
            const int col = wrow0[ni] + lr;
            #pragma unroll
            for (int mi = 0; mi < 4; ++mi) {
                int rowb = row0 + mi * 16 + lg * 4;
                #pragma unroll
                for (int r = 0; r < 4; ++r)
                    O[(size_t)(rowb + r) * HS + col] = f2bf(acc[mi][ni][r]);
            }
        } else {
            const int col = wrow0[ni] + lr;
            #pragma unroll
            for (int mi = 0; mi < 4; ++mi)
                #pragma unroll
                for (int r = 0; r < 4; ++r)
                    Cs[(mi * 16 + lg * 4 + r) * 136 + col] = f2bf(acc[mi][ni][r]);
        }
    }
    __syncthreads();
    {
        const int b  = row0 >> 12;
        const int n0 = row0 & (N_SEQ - 1);
        #pragma unroll
        for (int i = 0; i < 2; ++i) {
            int idx = tid + i * 512;          // [0,1024): 128 d x 8 chunks
            int d = idx >> 3, c8 = idx & 7;
            ushortv8 v;
            #pragma unroll
            for (int j = 0; j < 8; ++j)
                v[j] = Cs[(c8 * 8 + j) * 136 + d];
            *reinterpret_cast<ushortv8*>(Vt + (size_t)b * HS * N_SEQ + (size_t)d * N_SEQ + n0 + c8 * 8) = v;
        }
    }
}

// ---------------- flash attention: counted-vmcnt 3-buffer, split-st, VALU lsum ----------------
// grid (128, S), block 256 = 4 waves, 32 q-rows/wave. LDS = 3x(K 8KB + V 8KB) = 48 KB.
__global__ __launch_bounds__(256, 3) void attn_kernel(
    const unsigned short* __restrict__ Qb,
    const unsigned short* __restrict__ Kb,
    const unsigned short* __restrict__ Vt,
    unsigned short* __restrict__ part,   // [512][S][32][128] bf16
    float* __restrict__ plsum,           // [512][S][32]
    int S)
{
    const int qblk  = blockIdx.x;      // [0,128)
    const int split = blockIdx.y;      // [0,S)
    const int tid = threadIdx.x;
    const int wv = tid >> 6, lane = tid & 63;
    const int l31 = lane & 31, h = lane >> 5;
    const int b    = qblk >> 5;
    const int row0 = (qblk & 31) * 128 + wv * 32;

    __shared__ unsigned short Ks[3][KVB * 128];   // [kv][hd], slot16 ^= (kv&7)
    __shared__ unsigned short Vs[3][128 * KVB];   // [d][kv],  slot4  ^= ((d>>1)&3)

    // Q as B-fragment (pre-scaled by log2(e)/32 via castw)
    bf16x8 qf[8];
    {
        const unsigned short* qp = Qb + ((size_t)b * N_SEQ + row0 + l31) * HS + h * 8;
        #pragma unroll
        for (int kk = 0; kk < 8; ++kk)
            qf[kk] = *reinterpret_cast<const bf16x8*>(qp + kk * 16);
    }

    const int base = TT / S, rem = TT % S;
    const int nt = base + (split < rem ? 1 : 0);
    const int kv_begin = (split * base + (split < rem ? split : rem)) * KVB;

    const unsigned short* Kbb = Kb + (size_t)b * N_SEQ * HS;
    const unsigned short* Vbb = Vt + (size_t)b * HS * N_SEQ;

    auto stage = [&](int buf, int kv0) {
        #pragma unroll
        for (int i = 0; i < 2; ++i) {          // K [32][128]
            int g = wv * 2 + i;
            int r = g * 4 + (lane >> 4);
            int sp = (lane & 15) ^ (r & 7);
            gload16(Kbb + (size_t)(kv0 + r) * HS + sp * 8, &Ks[buf][g * 4 * 128]);
        }
        #pragma unroll
        for (int i = 0; i < 2; ++i) {          // V^T [128][32]
            int g = wv * 2 + i;
            int r = g * 16 + (lane >> 2);
            int sp = (lane & 3) ^ ((r >> 1) & 3);
            gload16(Vbb + (size_t)r * N_SEQ + kv0 + sp * 8, &Vs[buf][g * 16 * KVB]);
        }
    };

    f32x16 ctx[4] = {};
    float lsum = 0.f;

    stage(0, kv_begin);
    stage(1, kv_begin + KVB);
    int cur = 0, nxt = 2;
    for (int t = 0; t < nt; ++t) {
        if (t + 2 < nt) {
            asm volatile("s_waitcnt vmcnt(4)\n\ts_barrier" ::: "memory");
            stage(nxt, kv_begin + (t + 2) * KVB);
        } else if (t + 1 < nt) {
            asm volatile("s_waitcnt vmcnt(4)\n\ts_barrier" ::: "memory");
        } else {
            asm volatile("s_waitcnt vmcnt(0)\n\ts_barrier" ::: "memory");
        }

        // S^T = K Q^T (swapped), two independent accumulator chains
        f32x16 st0 = {}, st1 = {};
        __builtin_amdgcn_s_setprio(1);
        #pragma unroll
        for (int kk = 0; kk < 8; kk += 2) {
            bf16x8 kf0 = *reinterpret_cast<const bf16x8*>(
                &Ks[cur][l31 * 128 + (((kk * 2 + h) ^ (l31 & 7)) * 8)]);
            st0 = __builtin_amdgcn_mfma_f32_32x32x16_bf16(kf0, qf[kk], st0, 0, 0, 0);
            bf16x8 kf1 = *reinterpret_cast<const bf16x8*>(
                &Ks[cur][l31 * 128 + ((((kk + 1) * 2 + h) ^ (l31 & 7)) * 8)]);
            st1 = __builtin_amdgcn_mfma_f32_32x32x16_bf16(kf1, qf[kk + 1], st1, 0, 0, 0);
        }
        __builtin_amdgcn_s_setprio(0);

        float p[16];
        #pragma unroll
        for (int r = 0; r < 16; ++r)
            p[r] = __builtin_amdgcn_exp2f(st0[r] + st1[r]);

        {
            float a0 = (p[0] + p[1])   + (p[2] + p[3]);
            float a1 = (p[4] + p[5])   + (p[6] + p[7]);
            float a2 = (p[8] + p[9])   + (p[10] + p[11]);
            float a3 = (p[12] + p[13]) + (p[14] + p[15]);
            lsum += (a0 + a1) + (a2 + a3);
        }

        bf16x8 pf[2];
        #pragma unroll
        for (int half = 0; half < 2; ++half) {
            unsigned a  = cvtpk(p[half*8 + 0], p[half*8 + 1]);
            unsigned bq = cvtpk(p[half*8 + 2], p[half*8 + 3]);
            unsigned c  = cvtpk(p[half*8 + 4], p[half*8 + 5]);
            unsigned d  = cvtpk(p[half*8 + 6], p[half*8 + 7]);
            asm("v_permlane32_swap_b32 %0, %1" : "+v"(a), "+v"(c));
            asm("v_permlane32_swap_b32 %0, %1" : "+v"(bq), "+v"(d));
            uintv4 w = { a, bq, c, d };
            pf[half] = __builtin_bit_cast(bf16x8, w);
        }

        __builtin_amdgcn_s_setprio(1);
        #pragma unroll
        for (int dt = 0; dt < 4; ++dt) {
            int d = dt * 32 + l31;
            bf16x8 vf0 = *reinterpret_cast<const bf16x8*>(
                &Vs[cur][d * KVB + (((0 + h) ^ ((d >> 1) & 3)) * 8)]);
            ctx[dt] = __builtin_amdgcn_mfma_f32_32x32x16_bf16(pf[0], vf0, ctx[dt], 0, 0, 0);
            bf16x8 vf1 = *reinterpret_cast<const bf16x8*>(
                &Vs[cur][d * KVB + (((2 + h) ^ ((d >> 1) & 3)) * 8)]);
            ctx[dt] = __builtin_amdgcn_mfma_f32_32x32x16_bf16(pf[1], vf1, ctx[dt], 0, 0, 0);
        }
        __builtin_amdgcn_s_setprio(0);

        cur = (cur == 2) ? 0 : cur + 1;
        nxt = (nxt == 2) ? 0 : nxt + 1;
    }

    lsum += __shfl_xor(lsum, 32);

    const int qt = qblk * 4 + wv;              // [0,512) 32-row tile
    unsigned short* pp = part + ((size_t)qt * S + split) * (32 * 128);
    #pragma unroll
    for (int rp = 0; rp < 4; ++rp)
        #pragma unroll
        for (int rq = 0; rq < 4; ++rq) {
            const int r = rp * 4 + rq;
            const int q = rq + 8 * rp + 4 * h;
            #pragma unroll
            for (int dt = 0; dt < 4; ++dt)
                pp[q * 128 + dt * 32 + l31] = (unsigned short)(cvtpk(ctx[dt][r], ctx[dt][r]) & 0xFFFFu);
        }
    if (h == 0)
        plsum[((size_t)qt * S + split) * 32 + l31] = lsum;
}

// combine KV-split partials: out = (sum_s part_s) / (sum_s lsum_s)
__global__ __launch_bounds__(256) void reduce_kernel(
    const unsigned short* __restrict__ part,
    const float* __restrict__ plsum,
    float* __restrict__ out, int S)
{
    const int id = blockIdx.x * 256 + threadIdx.x;   // [0, 16384*128/4)
    const int d4 = (id & 31) * 4;
    const int grow = id >> 5;                        // global q row
    const int qt = grow >> 5, q = grow & 31;
    f32x4 c = {0.f, 0.f, 0.f, 0.f};
    float l = 0.f;
    for (int s = 0; s < S; ++s) {
        ushortv4 pv = *reinterpret_cast<const ushortv4*>(
            &part[(((size_t)qt * S + s) * 32 + q) * 128 + d4]);
        #pragma unroll
        for (int j = 0; j < 4; ++j)
            c[j] += __builtin_bit_cast(float, (unsigned)pv[j] << 16);
        l += plsum[((size_t)qt * S + s) * 32 + q];
    }
    float inv = 1.0f / l;
    f32x4 o = { c[0]*inv, c[1]*inv, c[2]*inv, c[3]*inv };
    *reinterpret_cast<f32x4*>(&out[(size_t)grow * 128 + d4]) = o;
}

extern "C" void kernel_launch(void* const* d_in, const int* in_sizes, int n_in,
                              void* d_out, int out_size, void* d_ws, size_t ws_size,
                              hipStream_t stream) {
    const float* x  = (const float*)d_in[0];
    const float* wq = (const float*)d_in[1];
    const float* wk = (const float*)d_in[2];
    const float* wv = (const float*)d_in[3];

    // ws layout: Wb2 | Qb | Kb | Vt | plsum(max S) | part
    unsigned short* Wb2 = (unsigned short*)d_ws;                // 0.79 MB
    unsigned short* Qb = Wb2 + (size_t)3 * HS * DIMK;
    unsigned short* Kb = Qb + (size_t)ROWS * HS;
    unsigned short* Vt = Kb + (size_t)ROWS * HS;
    float* plsum = (float*)(Vt + (size_t)N_B * HS * N_SEQ);

    const size_t fixed = (size_t)3 * HS * DIMK * 2 + (size_t)3 * ROWS * HS * 2;  // 13.4 MB
    const size_t per_split = (size_t)512 * 32 * 4 + (size_t)512 * 32 * 128 * 2;  // 4.26 MB

    int S;
    if      (ws_size >= fixed + 6 * per_split) S = 6;
    else if (ws_size >= fixed + 4 * per_split) S = 4;
    else if (ws_size >= fixed + 2 * per_split) S = 2;
    else                                       S = 1;

    unsigned short* part = (unsigned short*)(plsum + (size_t)512 * S * 32);

    castw_kernel<<<192, 256, 0, stream>>>(wq, wk, wv, Wb2);
    proj_kernel<<<256, 512, 0, stream>>>(x, Wb2, Qb, Kb, Vt);
    attn_kernel<<<dim3(128, S), 256, 0, stream>>>(Qb, Kb, Vt, part, plsum, S);
    reduce_kernel<<<(ROWS * HS) / 1024, 256, 0, stream>>>(part, plsum, (float*)d_out, S);
}